// Round 1
// baseline (356.922 us; speedup 1.0000x reference)
//
#include <hip/hip_runtime.h>

#define HH 128
#define WW 128
#define CIN 64
#define COUT 64

// ---------------------------------------------------------------------------
// Kernel 1: dense conv on the first i_first samples.
// Grid: (W/16, H/16, i_first * 4 co-groups). Block: 256 threads (16x16 tile).
// Each thread: one output pixel x 16 output channels.
// Weights read with block-uniform addresses -> s_load -> SGPR FMA operands.
// ---------------------------------------------------------------------------
constexpr int K1_NCO = 16;

__global__ __launch_bounds__(256) void conv_first(
    const float* __restrict__ x, const float* __restrict__ weight,
    const float* __restrict__ bias, float* __restrict__ out)
{
    __shared__ float tile[18][20];   // +pad to break power-of-2 stride
    const int tx = threadIdx.x & 15;
    const int ty = threadIdx.x >> 4;
    const int x0 = blockIdx.x * 16;
    const int y0 = blockIdx.y * 16;
    const int i   = blockIdx.z >> 2;   // sample
    const int cog = blockIdx.z & 3;    // group of 16 output channels

    float acc[K1_NCO];
#pragma unroll
    for (int c = 0; c < K1_NCO; ++c) acc[c] = 0.f;

    const float* xin = x + (size_t)i * CIN * HH * WW;

    for (int ci = 0; ci < CIN; ++ci) {
        const float* xp = xin + (size_t)ci * HH * WW;
        // stage 18x18 halo tile, zero-padded at borders
        for (int e = threadIdx.x; e < 18 * 18; e += 256) {
            int gy = e / 18, gx = e % 18;
            int yy = y0 + gy - 1, xx = x0 + gx - 1;
            float v = 0.f;
            if (yy >= 0 && yy < HH && xx >= 0 && xx < WW) v = xp[yy * WW + xx];
            tile[gy][gx] = v;
        }
        __syncthreads();

        float xv[9];
#pragma unroll
        for (int kh = 0; kh < 3; ++kh)
#pragma unroll
            for (int kw = 0; kw < 3; ++kw)
                xv[kh * 3 + kw] = tile[ty + kh][tx + kw];

        const float* wp = weight + ((size_t)(cog * K1_NCO) * CIN + ci) * 9;
#pragma unroll
        for (int c = 0; c < K1_NCO; ++c) {
            const float* wc = wp + (size_t)c * CIN * 9;   // block-uniform -> s_load
#pragma unroll
            for (int k = 0; k < 9; ++k)
                acc[c] = fmaf(xv[k], wc[k], acc[c]);
        }
        __syncthreads();
    }

    const int oy = y0 + ty, ox = x0 + tx;
#pragma unroll
    for (int c = 0; c < K1_NCO; ++c) {
        int co = cog * K1_NCO + c;
        float b = (i == 0) ? bias[co] : 0.f;
        out[(((size_t)i * COUT + co) * HH + oy) * WW + ox] = acc[c] + b;
    }
}

// ---------------------------------------------------------------------------
// Kernel 2: per-term single-channel convs (memory-bound, 537 MB of writes).
// Grid: (16 strips * 4 co-groups, T). Block: 256 threads.
// Each block: one term, one 8-row strip, 16 output channels.
// Each thread: 4 consecutive pixels, float4 store per channel.
// ---------------------------------------------------------------------------
constexpr int K2_NCO = 16;

__global__ __launch_bounds__(256) void conv_terms(
    const float* __restrict__ x, const float* __restrict__ weight,
    const int* __restrict__ term_errors, const int* __restrict__ term_feats,
    float* __restrict__ out, int i_first)
{
    __shared__ float tile[10][132];
    const int t     = blockIdx.y;
    const int strip = blockIdx.x & 15;
    const int cog   = blockIdx.x >> 4;
    const int e = term_errors[t];   // block-uniform -> scalar load
    const int f = term_feats[t];
    const float* xp = x + ((size_t)e * CIN + f) * HH * WW;
    const int y0 = strip * 8;

    // stage 10 rows x 130 cols (image cols -1..128), zero-padded
    for (int idx = threadIdx.x; idx < 10 * 130; idx += 256) {
        int gy = idx / 130, gx = idx % 130;
        int yy = y0 + gy - 1, xx = gx - 1;
        float v = 0.f;
        if (yy >= 0 && yy < HH && xx >= 0 && xx < WW) v = xp[yy * WW + xx];
        tile[gy][gx] = v;
    }
    __syncthreads();

    const int r  = threadIdx.x >> 5;          // row 0..7 within strip
    const int cq = (threadIdx.x & 31) * 4;    // output col 0..124

    float xv[3][6];
#pragma unroll
    for (int kh = 0; kh < 3; ++kh)
#pragma unroll
        for (int j = 0; j < 6; ++j)
            xv[kh][j] = tile[r + kh][cq + j];

    const int oy = y0 + r;
#pragma unroll
    for (int c = 0; c < K2_NCO; ++c) {
        int co = cog * K2_NCO + c;
        const float* wc = weight + ((size_t)co * CIN + f) * 9;  // uniform -> s_load
        float op[4];
#pragma unroll
        for (int p = 0; p < 4; ++p) {
            float s = 0.f;
#pragma unroll
            for (int kh = 0; kh < 3; ++kh)
#pragma unroll
                for (int kw = 0; kw < 3; ++kw)
                    s = fmaf(xv[kh][p + kw], wc[kh * 3 + kw], s);
            op[p] = s;
        }
        float4* dst = (float4*)&out[
            ((((size_t)(i_first + t)) * COUT + co) * HH + oy) * WW + cq];
        *dst = make_float4(op[0], op[1], op[2], op[3]);
    }
}

extern "C" void kernel_launch(void* const* d_in, const int* in_sizes, int n_in,
                              void* d_out, int out_size, void* d_ws, size_t ws_size,
                              hipStream_t stream) {
    const float* x          = (const float*)d_in[0];
    const float* weight     = (const float*)d_in[1];
    const float* bias       = (const float*)d_in[2];
    const int* term_errors  = (const int*)d_in[3];
    const int* term_feats   = (const int*)d_in[4];
    float* out = (float*)d_out;

    const int T = in_sizes[3];                      // 128
    const int n_out = out_size / (COUT * HH * WW);  // 136
    const int i_first = n_out - T;                  // 8

    dim3 g1(WW / 16, HH / 16, i_first * (COUT / K1_NCO));
    conv_first<<<g1, 256, 0, stream>>>(x, weight, bias, out);

    dim3 g2(16 * (COUT / K2_NCO), T);
    conv_terms<<<g2, 256, 0, stream>>>(x, weight, term_errors, term_feats,
                                       out, i_first);
}

// Round 2
// 171.625 us; speedup vs baseline: 2.0797x; 2.0797x over previous
//
#include <hip/hip_runtime.h>

#define HH 128
#define WW 128
#define CIN 64
#define COUT 64
#define NTAP 9

typedef __attribute__((ext_vector_type(8))) short bf16x8;   // 8 bf16 (4 VGPRs)
typedef __attribute__((ext_vector_type(4))) float f32x4;    // MFMA accumulator

__device__ inline ushort f2bf(float f) {
    union { float f; uint u; } v; v.f = f;
    uint u = v.u;
    return (ushort)((u + 0x7FFF + ((u >> 16) & 1)) >> 16);   // RNE
}

// ---------------------------------------------------------------------------
// Prep: pack weights into MFMA-fragment order, bf16, in d_ws.
// wfrag flat index = (((tap*2 + ks)*4 + f)*64 + lane)*8 + j
//   co = f*16 + (lane&15); ci = ks*32 + (lane>>4)*8 + j
// ---------------------------------------------------------------------------
__global__ void prep_w(const float* __restrict__ weight, ushort* __restrict__ wfrag) {
    int idx = blockIdx.x * 256 + threadIdx.x;
    if (idx >= NTAP * 2 * 4 * 64 * 8) return;
    int j  = idx & 7;
    int l  = (idx >> 3) & 63;
    int f  = (idx >> 9) & 3;
    int ks = (idx >> 11) & 1;
    int tp = idx >> 12;
    int co = f * 16 + (l & 15);
    int ci = ks * 32 + (l >> 4) * 8 + j;
    wfrag[idx] = f2bf(weight[((size_t)co * CIN + ci) * NTAP + tp]);
}

// ---------------------------------------------------------------------------
// Kernel 1: dense conv on first i_first samples via bf16 MFMA implicit GEMM.
// GEMM: D[co=64][x=128] = sum_k W[co][k] * A[k][x],  k = (ci, kh, kw).
// One block per (i, y): 256 threads = 4 waves; wave w owns x in [w*32, w*32+32).
// A_lds[kh][xs][ci] bf16, 16B-slot XOR swizzle: slot ^= (xs & 7).
// ---------------------------------------------------------------------------
__global__ __launch_bounds__(256, 3) void conv_first_mfma(
    const float* __restrict__ x, const ushort* __restrict__ wfrag,
    const float* __restrict__ bias, float* __restrict__ out)
{
    __shared__ ushort A[3 * 130 * 64];     // 49920 B, row stride 128 B
    // XCD-bijective swizzle: 1024 blocks, 8 XCDs -> one sample per XCD
    const int wg = (blockIdx.x & 7) * 128 + (blockIdx.x >> 3);
    const int i = wg >> 7;                 // sample 0..7
    const int y = wg & 127;                // output row
    const int t = threadIdx.x;

    // zero edge columns xs=0 and xs=129 (full 128B rows -> swizzle-safe)
    {
        uint* Az = (uint*)A;
        for (int e = t; e < 6 * 32; e += 256) {
            int rr = e >> 5;               // 0..5
            int kh = rr >> 1;
            int xs = (rr & 1) ? 129 : 0;
            Az[(kh * 130 + xs) * 32 + (e & 31)] = 0;
        }
    }

    // interior staging: 3 kh x 32 ci-pairs x 128 xs = 12288 tasks, 48/thread.
    // lane-consecutive xs -> coalesced global reads, ~4-way ds_write conflicts.
    const float* xi = x + (size_t)i * CIN * HH * WW;
    for (int it = 0; it < 48; ++it) {
        int flat = it * 256 + t;
        int xs = (flat & 127) + 1;         // 1..128  (x = xs-1)
        int cp = (flat >> 7) & 31;         // ci pair
        int kh = flat >> 12;               // 0..2
        int yy = y + kh - 1;
        uint v = 0;
        if (yy >= 0 && yy < HH) {
            const float* p = xi + ((size_t)(2 * cp) * HH + yy) * WW + (xs - 1);
            float lo = p[0];
            float hi = p[HH * WW];
            v = (uint)f2bf(lo) | ((uint)f2bf(hi) << 16);
        }
        int slot = (cp >> 2) ^ (xs & 7);
        ((uint*)A)[(kh * 130 + xs) * 32 + slot * 4 + (cp & 3)] = v;
    }
    __syncthreads();

    const int wv = t >> 6;                 // wave 0..3
    const int l  = t & 63;
    const int g  = l >> 4;                 // k-group
    const int ln = l & 15;
    const int xbase = wv * 32;

    f32x4 acc[4][2];
#pragma unroll
    for (int f = 0; f < 4; ++f)
#pragma unroll
        for (int xfi = 0; xfi < 2; ++xfi)
            acc[f][xfi] = (f32x4){0.f, 0.f, 0.f, 0.f};

    const bf16x8* Wp = (const bf16x8*)wfrag;
    const ushort* Ab = A;

#pragma unroll
    for (int tap = 0; tap < NTAP; ++tap) {
        const int kh = tap / 3, kw = tap % 3;
        // weight frags: per-lane b128 from L2-resident frag-ordered buffer
        bf16x8 wf[2][4];
#pragma unroll
        for (int ks = 0; ks < 2; ++ks)
#pragma unroll
            for (int f = 0; f < 4; ++f)
                wf[ks][f] = Wp[((tap * 2 + ks) * 4 + f) * 64 + l];
        // x frags from swizzled LDS (conflict-free b128)
        bf16x8 xf_[2][2];
#pragma unroll
        for (int xfi = 0; xfi < 2; ++xfi)
#pragma unroll
            for (int ks = 0; ks < 2; ++ks) {
                int xs = xbase + xfi * 16 + ln + kw;   // 0..129
                int slot = (ks * 4 + g) ^ (xs & 7);
                xf_[xfi][ks] = *(const bf16x8*)(Ab + (size_t)(kh * 130 + xs) * 64 + slot * 8);
            }
#pragma unroll
        for (int f = 0; f < 4; ++f)
#pragma unroll
            for (int xfi = 0; xfi < 2; ++xfi)
#pragma unroll
                for (int ks = 0; ks < 2; ++ks)
                    acc[f][xfi] = __builtin_amdgcn_mfma_f32_16x16x32_bf16(
                        wf[ks][f], xf_[xfi][ks], acc[f][xfi], 0, 0, 0);
    }

    // epilogue: D row = co = f*16 + g*4 + r ; D col = x = xbase + xfi*16 + ln
#pragma unroll
    for (int f = 0; f < 4; ++f) {
#pragma unroll
        for (int r = 0; r < 4; ++r) {
            int co = f * 16 + g * 4 + r;
            float b = (i == 0) ? bias[co] : 0.f;
#pragma unroll
            for (int xfi = 0; xfi < 2; ++xfi) {
                int xcol = xbase + xfi * 16 + ln;
                out[(((size_t)i * COUT + co) * HH + y) * WW + xcol] = acc[f][xfi][r] + b;
            }
        }
    }
}

// ---------------------------------------------------------------------------
// Kernel 2: per-term single-channel convs (write-bound, 537 MB).
// ---------------------------------------------------------------------------
constexpr int K2_NCO = 16;

__global__ __launch_bounds__(256) void conv_terms(
    const float* __restrict__ x, const float* __restrict__ weight,
    const int* __restrict__ term_errors, const int* __restrict__ term_feats,
    float* __restrict__ out, int i_first)
{
    __shared__ float tile[10][132];
    const int t     = blockIdx.y;
    const int strip = blockIdx.x & 15;
    const int cog   = blockIdx.x >> 4;
    const int e = term_errors[t];
    const int f = term_feats[t];
    const float* xp = x + ((size_t)e * CIN + f) * HH * WW;
    const int y0 = strip * 8;

    for (int idx = threadIdx.x; idx < 10 * 130; idx += 256) {
        int gy = idx / 130, gx = idx % 130;
        int yy = y0 + gy - 1, xx = gx - 1;
        float v = 0.f;
        if (yy >= 0 && yy < HH && xx >= 0 && xx < WW) v = xp[yy * WW + xx];
        tile[gy][gx] = v;
    }
    __syncthreads();

    const int r  = threadIdx.x >> 5;
    const int cq = (threadIdx.x & 31) * 4;

    float xv[3][6];
#pragma unroll
    for (int kh = 0; kh < 3; ++kh)
#pragma unroll
        for (int j = 0; j < 6; ++j)
            xv[kh][j] = tile[r + kh][cq + j];

    const int oy = y0 + r;
#pragma unroll
    for (int c = 0; c < K2_NCO; ++c) {
        int co = cog * K2_NCO + c;
        const float* wc = weight + ((size_t)co * CIN + f) * 9;
        float op[4];
#pragma unroll
        for (int p = 0; p < 4; ++p) {
            float s = 0.f;
#pragma unroll
            for (int kh = 0; kh < 3; ++kh)
#pragma unroll
                for (int kw = 0; kw < 3; ++kw)
                    s = fmaf(xv[kh][p + kw], wc[kh * 3 + kw], s);
            op[p] = s;
        }
        float4* dst = (float4*)&out[
            ((((size_t)(i_first + t)) * COUT + co) * HH + oy) * WW + cq];
        *dst = make_float4(op[0], op[1], op[2], op[3]);
    }
}

extern "C" void kernel_launch(void* const* d_in, const int* in_sizes, int n_in,
                              void* d_out, int out_size, void* d_ws, size_t ws_size,
                              hipStream_t stream) {
    const float* x          = (const float*)d_in[0];
    const float* weight     = (const float*)d_in[1];
    const float* bias       = (const float*)d_in[2];
    const int* term_errors  = (const int*)d_in[3];
    const int* term_feats   = (const int*)d_in[4];
    float* out = (float*)d_out;
    ushort* wfrag = (ushort*)d_ws;                  // 73728 B

    const int T = in_sizes[3];                      // 128
    const int n_out = out_size / (COUT * HH * WW);  // 136
    const int i_first = n_out - T;                  // 8

    prep_w<<<(NTAP * 2 * 4 * 64 * 8 + 255) / 256, 256, 0, stream>>>(weight, wfrag);

    conv_first_mfma<<<i_first * HH, 256, 0, stream>>>(x, wfrag, bias, out);

    dim3 g2(16 * (COUT / K2_NCO), T);
    conv_terms<<<g2, 256, 0, stream>>>(x, weight, term_errors, term_feats,
                                       out, i_first);
}